// Round 1
// baseline (926.826 us; speedup 1.0000x reference)
//
#include <hip/hip_runtime.h>
#include <hip/hip_bf16.h>

// Problem constants (match reference)
#define BB   256
#define SS   512
#define HH   512
#define EE   512
#define VV   50257
#define ENCC 1024
#define NBLK 393            // ceil(V/128)
#define VPAD (NBLK * 128)   // 50304, logits row stride (bf16) so full tiles never cross rows
#define SC   8              // s-chunks for context partial sums
#define VT   4096           // final-pass tile width
#define NT   13             // ceil(V/VT)

typedef __attribute__((ext_vector_type(8))) short short8_t;     // 8 bf16 = 4 VGPR (MFMA A/B frag)
typedef __attribute__((ext_vector_type(4))) float f32x4_t;      // MFMA C/D frag
typedef __attribute__((ext_vector_type(8))) unsigned short ushort8_t;

__device__ __forceinline__ unsigned short f2bf(float f) {       // fp32 -> bf16 RNE
  unsigned u = __builtin_bit_cast(unsigned, f);
  return (unsigned short)((u + 0x7fffu + ((u >> 16) & 1u)) >> 16);
}
__device__ __forceinline__ float bf2f(unsigned short s) {
  return __builtin_bit_cast(float, ((unsigned)s) << 16);
}

// K1: ctxp[b][sc][h] = sum_{s in chunk sc} attn[b,s] * enc[s,b,h]   (streams 512 MB)
__global__ __launch_bounds__(256) void ctx_partial_k(
    const float* __restrict__ attn, const float* __restrict__ enc,
    float* __restrict__ ctxp) {
  const int b = blockIdx.x, sc = blockIdx.y, t = threadIdx.x;
  const int h4 = t * 4;
  const int s0 = sc * (SS / SC);
  const float* ep = enc + (size_t)s0 * BB * ENCC + (size_t)b * ENCC + h4;
  const float* ap = attn + b * SS + s0;
  float4 acc = make_float4(0.f, 0.f, 0.f, 0.f);
#pragma unroll 4
  for (int i = 0; i < SS / SC; ++i) {
    float a = ap[i];                                  // block-uniform -> scalar load
    float4 e = *(const float4*)(ep + (size_t)i * BB * ENCC);
    acc.x += a * e.x; acc.y += a * e.y; acc.z += a * e.z; acc.w += a * e.w;
  }
  *(float4*)(ctxp + ((size_t)(b * SC + sc)) * ENCC + h4) = acc;
}

// K2: p_gen[b] = sigmoid([hidden, embed, ctx] . pgen_w + pgen_b)
__global__ __launch_bounds__(256) void pgen_k(
    const float* __restrict__ hidden, const float* __restrict__ embed,
    const float* __restrict__ ctxp, const float* __restrict__ pgw,
    const float* __restrict__ pgb, float* __restrict__ pgen) {
  const int b = blockIdx.x, t = threadIdx.x;
  float acc = 0.f;
  for (int h = t; h < HH; h += 256) acc += hidden[b * HH + h] * pgw[h];
  for (int h = t; h < EE; h += 256) acc += embed[b * EE + h] * pgw[HH + h];
  for (int h = t; h < ENCC; h += 256) {
    float c = 0.f;
#pragma unroll
    for (int p = 0; p < SC; ++p) c += ctxp[((size_t)(b * SC + p)) * ENCC + h];
    acc += c * pgw[HH + EE + h];
  }
#pragma unroll
  for (int off = 32; off; off >>= 1) acc += __shfl_xor(acc, off, 64);
  __shared__ float red[4];
  if ((t & 63) == 0) red[t >> 6] = acc;
  __syncthreads();
  if (t == 0) {
    float s = red[0] + red[1] + red[2] + red[3] + pgb[0];
    pgen[b] = 1.f / (1.f + __expf(-s));
  }
}

// K3: bf16 MFMA NT-GEMM (m97 structure): logit = x @ proj_w^T + proj_b
//     + per-(row, 128-col-block) softmax partials + bf16 logits to ws.
__global__ __launch_bounds__(256) void gemm_k(
    const float* __restrict__ x, const float* __restrict__ pw,
    const float* __restrict__ pb, unsigned short* __restrict__ logits,
    float* __restrict__ max_p, float* __restrict__ sum_p) {
  __shared__ unsigned short As[128 * 32];   // [row][k] bf16
  __shared__ unsigned short Bs[128 * 32];
  __shared__ float wred[2][128];
  __shared__ float bstat[128];

  const int mb = blockIdx.x, nb = blockIdx.y, t = threadIdx.x;
  const int wave = t >> 6, lane = t & 63;
  const int wm = wave >> 1, wn = wave & 1;       // 2x2 waves, 64x64 each
  const int quad = lane >> 4, l16 = lane & 15;
  const int m0 = mb * 128, n0 = nb * 128;
  const int srow = t >> 3, scol = (t & 7) * 4;   // staging: 32 rows x 8 float4 per pass

  f32x4_t acc[4][4] = {};

  for (int k0 = 0; k0 < HH; k0 += 32) {
    __syncthreads();
#pragma unroll
    for (int i = 0; i < 4; ++i) {
      int r = srow + 32 * i;
      float4 av = *(const float4*)(x + (size_t)(m0 + r) * HH + k0 + scol);
      ushort4 apk;
      apk.x = f2bf(av.x); apk.y = f2bf(av.y); apk.z = f2bf(av.z); apk.w = f2bf(av.w);
      *(ushort4*)&As[r * 32 + scol] = apk;
      int gn = n0 + r;
      float4 bv = make_float4(0.f, 0.f, 0.f, 0.f);
      if (gn < VV) bv = *(const float4*)(pw + (size_t)gn * HH + k0 + scol);
      ushort4 bpk;
      bpk.x = f2bf(bv.x); bpk.y = f2bf(bv.y); bpk.z = f2bf(bv.z); bpk.w = f2bf(bv.w);
      *(ushort4*)&Bs[r * 32 + scol] = bpk;
    }
    __syncthreads();
    short8_t af[4], bf[4];
#pragma unroll
    for (int i = 0; i < 4; ++i) {
      af[i] = *(const short8_t*)&As[(wm * 64 + i * 16 + l16) * 32 + quad * 8];
      bf[i] = *(const short8_t*)&Bs[(wn * 64 + i * 16 + l16) * 32 + quad * 8];
    }
#pragma unroll
    for (int i = 0; i < 4; ++i)
#pragma unroll
      for (int j = 0; j < 4; ++j)
        acc[i][j] = __builtin_amdgcn_mfma_f32_16x16x32_bf16(af[i], bf[j], acc[i][j], 0, 0, 0);
  }

  // epilogue: bias + mask cols >= V (C/D map: col = lane&15, row = quad*4 + reg)
  float bias[4];
  bool okc[4];
#pragma unroll
  for (int j = 0; j < 4; ++j) {
    int col = n0 + wn * 64 + j * 16 + l16;
    okc[j] = (col < VV);
    bias[j] = okc[j] ? pb[col] : 0.f;
  }
#pragma unroll
  for (int i = 0; i < 4; ++i)
#pragma unroll
    for (int j = 0; j < 4; ++j)
#pragma unroll
      for (int r = 0; r < 4; ++r)
        acc[i][j][r] = okc[j] ? (acc[i][j][r] + bias[j]) : -1e30f;

  // bf16 logits to ws (VPAD row stride: full 128-wide tiles never cross rows)
#pragma unroll
  for (int i = 0; i < 4; ++i)
#pragma unroll
    for (int j = 0; j < 4; ++j) {
      int col = n0 + wn * 64 + j * 16 + l16;
      int rowb = wm * 64 + i * 16 + quad * 4;
#pragma unroll
      for (int r = 0; r < 4; ++r)
        logits[(size_t)(m0 + rowb + r) * VPAD + col] = f2bf(acc[i][j][r]);
    }

  // per-row max over this 128-col block
  float rmax[4][4];
#pragma unroll
  for (int i = 0; i < 4; ++i)
#pragma unroll
    for (int r = 0; r < 4; ++r) {
      float m = fmaxf(fmaxf(acc[i][0][r], acc[i][1][r]), fmaxf(acc[i][2][r], acc[i][3][r]));
#pragma unroll
      for (int off = 1; off < 16; off <<= 1) m = fmaxf(m, __shfl_xor(m, off, 16));
      rmax[i][r] = m;
    }
  if (l16 == 0)
#pragma unroll
    for (int i = 0; i < 4; ++i)
#pragma unroll
      for (int r = 0; r < 4; ++r)
        wred[wn][wm * 64 + i * 16 + quad * 4 + r] = rmax[i][r];
  __syncthreads();
  if (t < 128) bstat[t] = fmaxf(wred[0][t], wred[1][t]);
  __syncthreads();

  // per-row sum of exp relative to block-local max
  float rsum[4][4];
#pragma unroll
  for (int i = 0; i < 4; ++i)
#pragma unroll
    for (int r = 0; r < 4; ++r) {
      float bm = bstat[wm * 64 + i * 16 + quad * 4 + r];
      float s = __expf(acc[i][0][r] - bm) + __expf(acc[i][1][r] - bm)
              + __expf(acc[i][2][r] - bm) + __expf(acc[i][3][r] - bm);
#pragma unroll
      for (int off = 1; off < 16; off <<= 1) s += __shfl_xor(s, off, 16);
      rsum[i][r] = s;
    }
  if (l16 == 0)
#pragma unroll
    for (int i = 0; i < 4; ++i)
#pragma unroll
      for (int r = 0; r < 4; ++r)
        wred[wn][wm * 64 + i * 16 + quad * 4 + r] = rsum[i][r];
  __syncthreads();
  if (t < 128) {
    int rg = m0 + t;
    max_p[rg * NBLK + nb] = bstat[t];
    sum_p[rg * NBLK + nb] = wred[0][t] + wred[1][t];
  }
}

// K4: reduce 393 partials -> row max m and 1/Z per row
__global__ __launch_bounds__(256) void rowstat_k(
    const float* __restrict__ max_p, const float* __restrict__ sum_p,
    float* __restrict__ row_m, float* __restrict__ row_iz) {
  const int b = blockIdx.x, t = threadIdx.x;
  __shared__ float red[4];
  __shared__ float bmv;
  float m = -1e30f;
  for (int nb = t; nb < NBLK; nb += 256) m = fmaxf(m, max_p[b * NBLK + nb]);
#pragma unroll
  for (int off = 32; off; off >>= 1) m = fmaxf(m, __shfl_xor(m, off, 64));
  if ((t & 63) == 0) red[t >> 6] = m;
  __syncthreads();
  if (t == 0) bmv = fmaxf(fmaxf(red[0], red[1]), fmaxf(red[2], red[3]));
  __syncthreads();
  const float bm = bmv;
  float z = 0.f;
  for (int nb = t; nb < NBLK; nb += 256)
    z += sum_p[b * NBLK + nb] * __expf(max_p[b * NBLK + nb] - bm);
#pragma unroll
  for (int off = 32; off; off >>= 1) z += __shfl_xor(z, off, 64);
  if ((t & 63) == 0) red[t >> 6] = z;
  __syncthreads();
  if (t == 0) {
    row_m[b] = bm;
    row_iz[b] = 1.f / (red[0] + red[1] + red[2] + red[3]);
  }
}

// K5: out[b,v] = log(pgen*softmax(logit)[v] + scatter((1-pgen)*attn)[v] + eps)
//     scatter handled per 4096-col tile via zeroed LDS + atomics; combined in regs.
__global__ __launch_bounds__(256) void final_k(
    const unsigned short* __restrict__ logits, const float* __restrict__ row_m,
    const float* __restrict__ row_iz, const float* __restrict__ pgen,
    const float* __restrict__ attn, const int* __restrict__ ids,
    float* __restrict__ out) {
  __shared__ float sl[VT];
  const int vt = blockIdx.x, b = blockIdx.y, t = threadIdx.x;
  const int v0 = vt * VT;
  for (int i = t; i < VT; i += 256) sl[i] = 0.f;
  const float m = row_m[b], iz = row_iz[b], pg = pgen[b];
  const float scale = pg * iz, pa = 1.f - pg;
  __syncthreads();
#pragma unroll
  for (int s = t; s < SS; s += 256) {
    int id = ids[b * SS + s];
    if (id >= v0 && id < v0 + VT) atomicAdd(&sl[id - v0], pa * attn[b * SS + s]);
  }
  float vals[16];
  const unsigned short* lp = logits + (size_t)b * VPAD + v0 + t * 16;
  ushort8_t p0 = *(const ushort8_t*)lp;        // 16B vector loads of bf16 logits
  ushort8_t p1 = *(const ushort8_t*)(lp + 8);
#pragma unroll
  for (int j = 0; j < 8; ++j) vals[j] = scale * __expf(bf2f(p0[j]) - m);
#pragma unroll
  for (int j = 0; j < 8; ++j) vals[8 + j] = scale * __expf(bf2f(p1[j]) - m);
  __syncthreads();
  const int vb = v0 + t * 16;
#pragma unroll
  for (int j = 0; j < 16; ++j) {
    int v = vb + j;
    if (v < VV) out[(size_t)b * VV + v] = __logf(vals[j] + sl[t * 16 + j] + 1e-40f);
  }
}

extern "C" void kernel_launch(void* const* d_in, const int* in_sizes, int n_in,
                              void* d_out, int out_size, void* d_ws, size_t ws_size,
                              hipStream_t stream) {
  const float* x      = (const float*)d_in[0];
  const float* embed  = (const float*)d_in[1];
  const float* hidden = (const float*)d_in[2];
  const float* enc    = (const float*)d_in[3];
  const float* attn   = (const float*)d_in[4];
  const int*   ids    = (const int*)d_in[5];
  const float* pw     = (const float*)d_in[6];
  const float* pb     = (const float*)d_in[7];
  const float* pgw    = (const float*)d_in[8];
  const float* pgb    = (const float*)d_in[9];
  float* out = (float*)d_out;

  // ws layout (~35 MB total)
  char* ws = (char*)d_ws;
  unsigned short* logits = (unsigned short*)ws;                 // B*VPAD bf16
  size_t off = (size_t)BB * VPAD * 2;                           // 25,755,648 (16B aligned)
  float* max_p = (float*)(ws + off); off += (size_t)BB * NBLK * 4;
  float* sum_p = (float*)(ws + off); off += (size_t)BB * NBLK * 4;
  float* ctxp  = (float*)(ws + off); off += (size_t)BB * SC * ENCC * 4;
  float* pgen  = (float*)(ws + off); off += BB * 4;
  float* row_m = (float*)(ws + off); off += BB * 4;
  float* row_iz = (float*)(ws + off);

  ctx_partial_k<<<dim3(BB, SC), 256, 0, stream>>>(attn, enc, ctxp);
  pgen_k<<<dim3(BB), 256, 0, stream>>>(hidden, embed, ctxp, pgw, pgb, pgen);
  gemm_k<<<dim3(2, NBLK), 256, 0, stream>>>(x, pw, pb, logits, max_p, sum_p);
  rowstat_k<<<dim3(BB), 256, 0, stream>>>(max_p, sum_p, row_m, row_iz);
  final_k<<<dim3(NT, BB), 256, 0, stream>>>(logits, row_m, row_iz, pgen, attn, ids, out);
}

// Round 2
// 823.227 us; speedup vs baseline: 1.1258x; 1.1258x over previous
//
#include <hip/hip_runtime.h>
#include <hip/hip_bf16.h>

// Problem constants (match reference)
#define BB   256
#define SS   512
#define HH   512
#define EE   512
#define VV   50257
#define ENCC 1024
#define NBLK 393            // ceil(V/128)
#define VPAD (NBLK * 128)   // 50304, logits row stride (bf16)
#define SC   8              // s-chunks for context partial sums
#define VT   4096           // final-pass tile width
#define NT   13             // ceil(V/VT)

typedef __attribute__((ext_vector_type(8))) short short8_t;     // 8 bf16 = 4 VGPR (MFMA A/B frag)
typedef __attribute__((ext_vector_type(4))) float f32x4_t;      // MFMA C/D frag
typedef __attribute__((ext_vector_type(8))) unsigned short ushort8_t;

typedef __attribute__((address_space(1))) const void gv_t;      // global
typedef __attribute__((address_space(3))) void lv_t;            // LDS

__device__ __forceinline__ unsigned short f2bf(float f) {       // fp32 -> bf16 RNE
  unsigned u = __builtin_bit_cast(unsigned, f);
  return (unsigned short)((u + 0x7fffu + ((u >> 16) & 1u)) >> 16);
}
__device__ __forceinline__ float bf2f(unsigned short s) {
  return __builtin_bit_cast(float, ((unsigned)s) << 16);
}

// K0: x fp32 -> bf16 (256x512, 256 KB out) so gemm can global_load_lds the A operand
__global__ __launch_bounds__(256) void cvt_x_k(const float* __restrict__ x,
                                               unsigned short* __restrict__ xbf) {
  int i = (blockIdx.x * 256 + threadIdx.x) * 4;
  float4 v = *(const float4*)(x + i);
  ushort4 p;
  p.x = f2bf(v.x); p.y = f2bf(v.y); p.z = f2bf(v.z); p.w = f2bf(v.w);
  *(ushort4*)(xbf + i) = p;
}

// K1: ctxp[b][sc][h] = sum_{s in chunk sc} attn[b,s] * enc[s,b,h]   (streams 512 MB)
__global__ __launch_bounds__(256) void ctx_partial_k(
    const float* __restrict__ attn, const float* __restrict__ enc,
    float* __restrict__ ctxp) {
  const int b = blockIdx.x, sc = blockIdx.y, t = threadIdx.x;
  const int h4 = t * 4;
  const int s0 = sc * (SS / SC);
  const float* ep = enc + (size_t)s0 * BB * ENCC + (size_t)b * ENCC + h4;
  const float* ap = attn + b * SS + s0;
  float4 acc = make_float4(0.f, 0.f, 0.f, 0.f);
#pragma unroll 4
  for (int i = 0; i < SS / SC; ++i) {
    float a = ap[i];                                  // block-uniform -> scalar load
    float4 e = *(const float4*)(ep + (size_t)i * BB * ENCC);
    acc.x += a * e.x; acc.y += a * e.y; acc.z += a * e.z; acc.w += a * e.w;
  }
  *(float4*)(ctxp + ((size_t)(b * SC + sc)) * ENCC + h4) = acc;
}

// K2: p_gen[b] = sigmoid([hidden, embed, ctx] . pgen_w + pgen_b)
__global__ __launch_bounds__(256) void pgen_k(
    const float* __restrict__ hidden, const float* __restrict__ embed,
    const float* __restrict__ ctxp, const float* __restrict__ pgw,
    const float* __restrict__ pgb, float* __restrict__ pgen) {
  const int b = blockIdx.x, t = threadIdx.x;
  float acc = 0.f;
  for (int h = t; h < HH; h += 256) acc += hidden[b * HH + h] * pgw[h];
  for (int h = t; h < EE; h += 256) acc += embed[b * EE + h] * pgw[HH + h];
  for (int h = t; h < ENCC; h += 256) {
    float c = 0.f;
#pragma unroll
    for (int p = 0; p < SC; ++p) c += ctxp[((size_t)(b * SC + p)) * ENCC + h];
    acc += c * pgw[HH + EE + h];
  }
#pragma unroll
  for (int off = 32; off; off >>= 1) acc += __shfl_xor(acc, off, 64);
  __shared__ float red[4];
  if ((t & 63) == 0) red[t >> 6] = acc;
  __syncthreads();
  if (t == 0) {
    float s = red[0] + red[1] + red[2] + red[3] + pgb[0];
    pgen[b] = 1.f / (1.f + __expf(-s));
  }
}

// K3: bf16 MFMA NT-GEMM, M-tile=256 (pw read ONCE), 512 threads, 8 waves 4x2.
//     A staged via global_load_lds (bf16, no VALU); B staged fp32->bf16 in regs.
//     + per-(row, 128-col-block) softmax partials + bf16 logits to ws.
__global__ __launch_bounds__(512) void gemm_k(
    const unsigned short* __restrict__ xbf, const float* __restrict__ pw,
    const float* __restrict__ pb, unsigned short* __restrict__ logits,
    float* __restrict__ max_p, float* __restrict__ sum_p) {
  __shared__ unsigned short As[256 * 32];   // [row][k] bf16, 16 KB
  __shared__ unsigned short Bs[128 * 32];   // 8 KB
  __shared__ float wred[2][256];
  __shared__ float bstat[256];

  const int nb = blockIdx.x, t = threadIdx.x;
  const int wave = t >> 6, lane = t & 63;
  const int wm = wave >> 1, wn = wave & 1;       // 4x2 waves, 64x64 each
  const int quad = lane >> 4, l16 = lane & 15;
  const int n0 = nb * 128;
  const int br = t >> 2, bc = (t & 3) * 8;       // B chunk: row t/4, col (t%3)*8

  f32x4_t acc[4][4] = {};

  for (int k0 = 0; k0 < HH; k0 += 32) {
    // B global loads first (regs, no LDS dependency)
    const int gn = n0 + br;
    float4 b0 = make_float4(0.f, 0.f, 0.f, 0.f), b1 = b0;
    if (gn < VV) {
      b0 = *(const float4*)(pw + (size_t)gn * HH + k0 + bc);
      b1 = *(const float4*)(pw + (size_t)gn * HH + k0 + bc + 4);
    }
    __syncthreads();                              // prev-iter frag reads done
    // A: async global->LDS, width 16. chunk c = q*512 + wave*64 + lane;
    // LDS dest = base + lane*16 lands exactly at As[c*8] = As[row*32 + (c&3)*8].
#pragma unroll
    for (int q = 0; q < 2; ++q) {
      const int c = q * 512 + wave * 64 + lane;
      const unsigned short* ga = xbf + ((c >> 2) * HH + k0 + (c & 3) * 8);
      __builtin_amdgcn_global_load_lds((gv_t*)ga, (lv_t*)(As + (size_t)(q * 512 + wave * 64) * 8),
                                       16, 0, 0);
    }
    ushort8_t pk;
    pk[0] = f2bf(b0.x); pk[1] = f2bf(b0.y); pk[2] = f2bf(b0.z); pk[3] = f2bf(b0.w);
    pk[4] = f2bf(b1.x); pk[5] = f2bf(b1.y); pk[6] = f2bf(b1.z); pk[7] = f2bf(b1.w);
    *(ushort8_t*)&Bs[(size_t)t * 8] = pk;         // Bs[br*32 + bc]
    __syncthreads();
    short8_t af[4], bf[4];
#pragma unroll
    for (int i = 0; i < 4; ++i) {
      af[i] = *(const short8_t*)&As[(wm * 64 + i * 16 + l16) * 32 + quad * 8];
      bf[i] = *(const short8_t*)&Bs[(wn * 64 + i * 16 + l16) * 32 + quad * 8];
    }
#pragma unroll
    for (int i = 0; i < 4; ++i)
#pragma unroll
      for (int j = 0; j < 4; ++j)
        acc[i][j] = __builtin_amdgcn_mfma_f32_16x16x32_bf16(af[i], bf[j], acc[i][j], 0, 0, 0);
  }

  // epilogue: bias + mask cols >= V (C/D map: col = lane&15, row = quad*4 + reg)
  float bias[4];
  bool okc[4];
#pragma unroll
  for (int j = 0; j < 4; ++j) {
    int col = n0 + wn * 64 + j * 16 + l16;
    okc[j] = (col < VV);
    bias[j] = okc[j] ? pb[col] : 0.f;
  }
#pragma unroll
  for (int i = 0; i < 4; ++i)
#pragma unroll
    for (int j = 0; j < 4; ++j)
#pragma unroll
      for (int r = 0; r < 4; ++r)
        acc[i][j][r] = okc[j] ? (acc[i][j][r] + bias[j]) : -1e30f;

  // bf16 logits to ws (row = batch index directly, rows 0..255 covered by wm/quad)
#pragma unroll
  for (int i = 0; i < 4; ++i)
#pragma unroll
    for (int j = 0; j < 4; ++j) {
      int col = n0 + wn * 64 + j * 16 + l16;
      int rowb = wm * 64 + i * 16 + quad * 4;
#pragma unroll
      for (int r = 0; r < 4; ++r)
        logits[(size_t)(rowb + r) * VPAD + col] = f2bf(acc[i][j][r]);
    }

  // per-row max over this 128-col block
  float rmax[4][4];
#pragma unroll
  for (int i = 0; i < 4; ++i)
#pragma unroll
    for (int r = 0; r < 4; ++r) {
      float m = fmaxf(fmaxf(acc[i][0][r], acc[i][1][r]), fmaxf(acc[i][2][r], acc[i][3][r]));
#pragma unroll
      for (int off = 1; off < 16; off <<= 1) m = fmaxf(m, __shfl_xor(m, off, 16));
      rmax[i][r] = m;
    }
  if (l16 == 0)
#pragma unroll
    for (int i = 0; i < 4; ++i)
#pragma unroll
      for (int r = 0; r < 4; ++r)
        wred[wn][wm * 64 + i * 16 + quad * 4 + r] = rmax[i][r];
  __syncthreads();
  if (t < 256) bstat[t] = fmaxf(wred[0][t], wred[1][t]);
  __syncthreads();

  // per-row sum of exp relative to block-local max
  float rsum[4][4];
#pragma unroll
  for (int i = 0; i < 4; ++i)
#pragma unroll
    for (int r = 0; r < 4; ++r) {
      float bm = bstat[wm * 64 + i * 16 + quad * 4 + r];
      float s = __expf(acc[i][0][r] - bm) + __expf(acc[i][1][r] - bm)
              + __expf(acc[i][2][r] - bm) + __expf(acc[i][3][r] - bm);
#pragma unroll
      for (int off = 1; off < 16; off <<= 1) s += __shfl_xor(s, off, 16);
      rsum[i][r] = s;
    }
  if (l16 == 0)
#pragma unroll
    for (int i = 0; i < 4; ++i)
#pragma unroll
      for (int r = 0; r < 4; ++r)
        wred[wn][wm * 64 + i * 16 + quad * 4 + r] = rsum[i][r];
  __syncthreads();
  if (t < 256) {
    max_p[t * NBLK + nb] = bstat[t];
    sum_p[t * NBLK + nb] = wred[0][t] + wred[1][t];
  }
}

// K4: reduce 393 partials -> row max m and 1/Z per row
__global__ __launch_bounds__(256) void rowstat_k(
    const float* __restrict__ max_p, const float* __restrict__ sum_p,
    float* __restrict__ row_m, float* __restrict__ row_iz) {
  const int b = blockIdx.x, t = threadIdx.x;
  __shared__ float red[4];
  __shared__ float bmv;
  float m = -1e30f;
  for (int nb = t; nb < NBLK; nb += 256) m = fmaxf(m, max_p[b * NBLK + nb]);
#pragma unroll
  for (int off = 32; off; off >>= 1) m = fmaxf(m, __shfl_xor(m, off, 64));
  if ((t & 63) == 0) red[t >> 6] = m;
  __syncthreads();
  if (t == 0) bmv = fmaxf(fmaxf(red[0], red[1]), fmaxf(red[2], red[3]));
  __syncthreads();
  const float bm = bmv;
  float z = 0.f;
  for (int nb = t; nb < NBLK; nb += 256)
    z += sum_p[b * NBLK + nb] * __expf(max_p[b * NBLK + nb] - bm);
#pragma unroll
  for (int off = 32; off; off >>= 1) z += __shfl_xor(z, off, 64);
  if ((t & 63) == 0) red[t >> 6] = z;
  __syncthreads();
  if (t == 0) {
    row_m[b] = bm;
    row_iz[b] = 1.f / (red[0] + red[1] + red[2] + red[3]);
  }
}

// K5: out[b,v] = log(pgen*softmax(logit)[v] + scatter((1-pgen)*attn)[v] + eps)
__global__ __launch_bounds__(256) void final_k(
    const unsigned short* __restrict__ logits, const float* __restrict__ row_m,
    const float* __restrict__ row_iz, const float* __restrict__ pgen,
    const float* __restrict__ attn, const int* __restrict__ ids,
    float* __restrict__ out) {
  __shared__ float sl[VT];
  const int vt = blockIdx.x, b = blockIdx.y, t = threadIdx.x;
  const int v0 = vt * VT;
  for (int i = t; i < VT; i += 256) sl[i] = 0.f;
  const float m = row_m[b], iz = row_iz[b], pg = pgen[b];
  const float scale = pg * iz, pa = 1.f - pg;
  __syncthreads();
#pragma unroll
  for (int s = t; s < SS; s += 256) {
    int id = ids[b * SS + s];
    if (id >= v0 && id < v0 + VT) atomicAdd(&sl[id - v0], pa * attn[b * SS + s]);
  }
  float vals[16];
  const unsigned short* lp = logits + (size_t)b * VPAD + v0 + t * 16;
  ushort8_t p0 = *(const ushort8_t*)lp;        // 16B vector loads of bf16 logits
  ushort8_t p1 = *(const ushort8_t*)(lp + 8);
#pragma unroll
  for (int j = 0; j < 8; ++j) vals[j] = scale * __expf(bf2f(p0[j]) - m);
#pragma unroll
  for (int j = 0; j < 8; ++j) vals[8 + j] = scale * __expf(bf2f(p1[j]) - m);
  __syncthreads();
  const int vb = v0 + t * 16;
  float r[16];
#pragma unroll
  for (int j = 0; j < 16; ++j) r[j] = __logf(vals[j] + sl[t * 16 + j] + 1e-40f);
  if (vb + 15 < VV) {                           // full tile: float4 stores
    float* op = out + (size_t)b * VV + vb;
#pragma unroll
    for (int j = 0; j < 4; ++j)
      *(float4*)(op + j * 4) = make_float4(r[j * 4], r[j * 4 + 1], r[j * 4 + 2], r[j * 4 + 3]);
  } else {
#pragma unroll
    for (int j = 0; j < 16; ++j)
      if (vb + j < VV) out[(size_t)b * VV + vb + j] = r[j];
  }
}

extern "C" void kernel_launch(void* const* d_in, const int* in_sizes, int n_in,
                              void* d_out, int out_size, void* d_ws, size_t ws_size,
                              hipStream_t stream) {
  const float* x      = (const float*)d_in[0];
  const float* embed  = (const float*)d_in[1];
  const float* hidden = (const float*)d_in[2];
  const float* enc    = (const float*)d_in[3];
  const float* attn   = (const float*)d_in[4];
  const int*   ids    = (const int*)d_in[5];
  const float* pw     = (const float*)d_in[6];
  const float* pb     = (const float*)d_in[7];
  const float* pgw    = (const float*)d_in[8];
  const float* pgb    = (const float*)d_in[9];
  float* out = (float*)d_out;

  // ws layout (~35.2 MB total)
  char* ws = (char*)d_ws;
  unsigned short* logits = (unsigned short*)ws;                 // B*VPAD bf16
  size_t off = (size_t)BB * VPAD * 2;                           // 25,755,648 (16B aligned)
  float* max_p = (float*)(ws + off); off += (size_t)BB * NBLK * 4;
  float* sum_p = (float*)(ws + off); off += (size_t)BB * NBLK * 4;
  float* ctxp  = (float*)(ws + off); off += (size_t)BB * SC * ENCC * 4;
  float* pgen  = (float*)(ws + off); off += BB * 4;
  float* row_m = (float*)(ws + off); off += BB * 4;
  float* row_iz = (float*)(ws + off); off += BB * 4;
  unsigned short* xbf = (unsigned short*)(ws + off);            // 256 KB, 16B aligned

  cvt_x_k<<<dim3((BB * HH) / 1024), 256, 0, stream>>>(x, xbf);
  ctx_partial_k<<<dim3(BB, SC), 256, 0, stream>>>(attn, enc, ctxp);
  pgen_k<<<dim3(BB), 256, 0, stream>>>(hidden, embed, ctxp, pgw, pgb, pgen);
  gemm_k<<<dim3(NBLK), 512, 0, stream>>>(xbf, pw, pb, logits, max_p, sum_p);
  rowstat_k<<<dim3(BB), 256, 0, stream>>>(max_p, sum_p, row_m, row_iz);
  final_k<<<dim3(NT, BB), 256, 0, stream>>>(logits, row_m, row_iz, pgen, attn, ids, out);
}